// Round 1
// baseline (472.620 us; speedup 1.0000x reference)
//
#include <hip/hip_runtime.h>
#include <cstdint>

#define NENT 100000
#define EPS 1e-5f

// ---- ws layout (float offsets) ----
constexpr long REL_A    = 0;        // 2500
constexpr long REL_B    = 2500;     // 2500
constexpr long EAB      = 5000;     // 2  (a0, c0)
constexpr long A1O      = 5008;     // 100
constexpr long C1O      = 5108;     // 100
constexpr long A2O      = 5208;     // 100
constexpr long C2O      = 5308;     // 100
constexpr long PART_OFF = 5504;     // 4*1024*100 = 409600
constexpr long FCOUT_OFF= 415104;   // 1024*100   = 102400
constexpr long XBUF_OFF = 517504;   // 1024*3600  = 3686400
constexpr long XHAT_OFF = 4203904;  // 1024*128 bf16 = 65536 floats

typedef __attribute__((ext_vector_type(8))) __bf16 bf16x8;
typedef __attribute__((ext_vector_type(4))) float  f32x4;

__device__ __forceinline__ unsigned short f2bf(float f) {
    unsigned int u = __float_as_uint(f);
    unsigned int r = (u + 0x7FFFu + ((u >> 16) & 1u)) >> 16;
    return (unsigned short)r;
}

// K1: per-feature BN stats of gathered rel rows -> scale/shift (a,b)
__global__ void k_rel_stats(const int* __restrict__ rel, const float* __restrict__ emb_rel,
                            const float* __restrict__ grel, const float* __restrict__ brel,
                            float* __restrict__ ws) {
    __shared__ int ridx[1024];
    __shared__ float psum[256], psq[256];
    int tid = threadIdx.x;
    for (int i = tid; i < 1024; i += 256) ridx[i] = rel[i];
    __syncthreads();
    int fl = tid & 63, bl = tid >> 6;
    int f = blockIdx.x * 64 + fl;
    float s = 0.f, q = 0.f;
    if (f < 2500) {
#pragma unroll 4
        for (int b = bl; b < 1024; b += 4) {
            float v = emb_rel[(long)ridx[b] * 2500 + f];
            s += v; q += v * v;
        }
    }
    psum[tid] = s; psq[tid] = q;
    __syncthreads();
    if (tid < 64 && f < 2500) {
        float ss = psum[tid] + psum[tid + 64] + psum[tid + 128] + psum[tid + 192];
        float qq = psq[tid]  + psq[tid + 64]  + psq[tid + 128]  + psq[tid + 192];
        float mean = ss * (1.f / 1024.f);
        float var  = qq * (1.f / 1024.f) - mean * mean;
        float a = grel[f] * rsqrtf(var + EPS);
        ws[REL_A + f] = a;
        ws[REL_B + f] = brel[f] - mean * a;
    }
}

// K2: scalar BN stats of gathered e rows
__global__ void k_e_stats(const int* __restrict__ e1, const float* __restrict__ emb_e,
                          const float* __restrict__ g0, const float* __restrict__ b0,
                          float* __restrict__ ws) {
    __shared__ int eidx[1024];
    __shared__ float ps[1024], pq[1024];
    int tid = threadIdx.x;   // block of 1024
    eidx[tid] = e1[tid];
    __syncthreads();
    float s = 0.f, q = 0.f;
    for (int i = tid; i < 1024 * 100; i += 1024) {
        int b = i / 100, d = i - b * 100;
        float v = emb_e[(long)eidx[b] * 100 + d];
        s += v; q += v * v;
    }
    ps[tid] = s; pq[tid] = q;
    __syncthreads();
    for (int off = 512; off > 0; off >>= 1) {
        if (tid < off) { ps[tid] += ps[tid + off]; pq[tid] += pq[tid + off]; }
        __syncthreads();
    }
    if (tid == 0) {
        float mean = ps[0] * (1.f / 102400.f);
        float var  = pq[0] * (1.f / 102400.f) - mean * mean;
        float a = g0[0] * rsqrtf(var + EPS);
        ws[EAB]     = a;
        ws[EAB + 1] = b0[0] - mean * a;
    }
}

// K3: per-sample grouped conv 10x10 * (100 x 5x5) -> [B,100,6,6]
__global__ void k_conv(const int* __restrict__ e1, const int* __restrict__ rel,
                       const float* __restrict__ emb_e, const float* __restrict__ emb_rel,
                       const float* __restrict__ ws, float* __restrict__ xout) {
    __shared__ float es[100];
    __shared__ float flt[2500];
    int b = blockIdx.x, tid = threadIdx.x;
    float a0 = ws[EAB], c0 = ws[EAB + 1];
    long ebase = (long)e1[b] * 100;
    for (int i = tid; i < 100; i += 256) es[i] = a0 * emb_e[ebase + i] + c0;
    long rbase = (long)rel[b] * 2500;
    for (int i = tid; i < 2500; i += 256) flt[i] = ws[REL_A + i] * emb_rel[rbase + i] + ws[REL_B + i];
    __syncthreads();
    for (int u = tid; u < 600; u += 256) {
        int f = u / 6, oi = u - f * 6;
        float er[5][10];
#pragma unroll
        for (int p = 0; p < 5; p++)
#pragma unroll
            for (int c = 0; c < 10; c++) er[p][c] = es[(oi + p) * 10 + c];
        float fw[25];
#pragma unroll
        for (int k = 0; k < 25; k++) fw[k] = flt[f * 25 + k];
        float* dst = xout + (long)b * 3600 + f * 36 + oi * 6;
#pragma unroll
        for (int oj = 0; oj < 6; oj++) {
            float acc = 0.f;
#pragma unroll
            for (int p = 0; p < 5; p++)
#pragma unroll
                for (int q = 0; q < 5; q++) acc += er[p][oj + q] * fw[p * 5 + q];
            dst[oj] = acc;
        }
    }
}

// K4: per-channel BN1 stats over conv output
__global__ void k_bn1_stats(const float* __restrict__ xbuf, const float* __restrict__ g1,
                            const float* __restrict__ b1, float* __restrict__ ws) {
    __shared__ float ps[256], pq[256];
    int f = blockIdx.x, tid = threadIdx.x;
    float s = 0.f, q = 0.f;
    for (int i = tid; i < 1024 * 36; i += 256) {
        int b = i / 36, o = i - b * 36;
        float v = xbuf[(long)b * 3600 + f * 36 + o];
        s += v; q += v * v;
    }
    ps[tid] = s; pq[tid] = q;
    __syncthreads();
    for (int off = 128; off > 0; off >>= 1) {
        if (tid < off) { ps[tid] += ps[tid + off]; pq[tid] += pq[tid + off]; }
        __syncthreads();
    }
    if (tid == 0) {
        float mean = ps[0] * (1.f / 36864.f);
        float var  = pq[0] * (1.f / 36864.f) - mean * mean;
        float a = g1[f] * rsqrtf(var + EPS);
        ws[A1O + f] = a;
        ws[C1O + f] = b1[f] - mean * a;
    }
}

// K5: FC partials, K split in 4 chunks of 900.  block = (4 samples, 1 k-chunk)
__global__ void k_fc(const float* __restrict__ xbuf, const float* __restrict__ fc_w,
                     const float* __restrict__ ws, float* __restrict__ part) {
    __shared__ float a1s[100], c1s[100];
    __shared__ float xs[4][900];
    int tid = threadIdx.x;
    int sb = blockIdx.x, kc = blockIdx.y;
    if (tid < 100) { a1s[tid] = ws[A1O + tid]; c1s[tid] = ws[C1O + tid]; }
    __syncthreads();
    int b0 = sb * 4, k0 = kc * 900;
    for (int idx = tid; idx < 3600; idx += 256) {
        int s = idx / 900, k = idx - s * 900;
        int kg = k0 + k;
        int f = kg / 36;
        float v = xbuf[(long)(b0 + s) * 3600 + kg];
        v = a1s[f] * v + c1s[f];
        xs[s][k] = v > 0.f ? v : 0.f;
    }
    __syncthreads();
    if (tid < 200) {
        int j = tid % 100, sg = tid / 100;
        float acc0 = 0.f, acc1 = 0.f;
        const float4* wrow = (const float4*)(fc_w + (long)j * 3600 + k0);
        const float4* x0 = (const float4*)(&xs[sg][0]);
        const float4* x1 = (const float4*)(&xs[sg + 2][0]);
#pragma unroll 5
        for (int kk = 0; kk < 225; kk++) {
            float4 w4 = wrow[kk];
            float4 a4 = x0[kk], b4 = x1[kk];
            acc0 += w4.x * a4.x + w4.y * a4.y + w4.z * a4.z + w4.w * a4.w;
            acc1 += w4.x * b4.x + w4.y * b4.y + w4.z * b4.z + w4.w * b4.w;
        }
        part[((long)kc * 1024 + b0 + sg) * 100 + j]     = acc0;
        part[((long)kc * 1024 + b0 + sg + 2) * 100 + j] = acc1;
    }
}

// K6: combine FC partials + fc_b, per-feature BN2 stats
__global__ void k_bn2(const float* __restrict__ part, const float* __restrict__ fc_b,
                      const float* __restrict__ g2, const float* __restrict__ b2,
                      float* __restrict__ fcout, float* __restrict__ ws) {
    __shared__ float ps[256], pq[256];
    int j = blockIdx.x, tid = threadIdx.x;
    float s = 0.f, q = 0.f;
    for (int b = tid; b < 1024; b += 256) {
        float v = part[(long)b * 100 + j] + part[(long)(1024 + b) * 100 + j]
                + part[(long)(2048 + b) * 100 + j] + part[(long)(3072 + b) * 100 + j]
                + fc_b[j];
        fcout[(long)b * 100 + j] = v;
        s += v; q += v * v;
    }
    ps[tid] = s; pq[tid] = q;
    __syncthreads();
    for (int off = 128; off > 0; off >>= 1) {
        if (tid < off) { ps[tid] += ps[tid + off]; pq[tid] += pq[tid + off]; }
        __syncthreads();
    }
    if (tid == 0) {
        float mean = ps[0] * (1.f / 1024.f);
        float var  = pq[0] * (1.f / 1024.f) - mean * mean;
        float a = g2[j] * rsqrtf(var + EPS);
        ws[A2O + j] = a;
        ws[C2O + j] = b2[j] - mean * a;
    }
}

// K7: BN2-apply + ReLU -> xhat bf16 [1024][128] (zero-padded K)
__global__ void k_xhat(const float* __restrict__ fcout, const float* __restrict__ ws,
                       unsigned short* __restrict__ xhat) {
    int idx = blockIdx.x * 256 + threadIdx.x;  // grid 512 -> 131072
    int b = idx >> 7, k = idx & 127;
    float v = 0.f;
    if (k < 100) {
        v = ws[A2O + k] * fcout[(long)b * 100 + k] + ws[C2O + k];
        v = v > 0.f ? v : 0.f;
    }
    xhat[idx] = f2bf(v);
}

// K8: logits = Xhat @ emb_e^T + bias, sigmoid.  M=1024 N=100000 K=128(pad)
__global__ void __launch_bounds__(256, 2)
k_gemm(const unsigned short* __restrict__ xhat, const float* __restrict__ emb_e,
       const float* __restrict__ bias, float* __restrict__ out) {
    __shared__ __align__(16) unsigned short Es[256 * 128];  // row-major [256][128] bf16, XOR-swizzled
    int tid = threadIdx.x;
    int m0 = blockIdx.x * 64;
    int n0 = blockIdx.y * 256;

    // ---- stage E tile (fp32 -> bf16, swizzle byte ^= (row&7)<<4) ----
    {
        int p = tid & 3;
        int rbase = tid >> 2;  // 0..63
        for (int rr = 0; rr < 4; rr++) {
            int r = rr * 64 + rbase;
            int g = n0 + r;
            unsigned int rowb = (unsigned)r * 256u;
            unsigned int sw = ((unsigned)r & 7u) << 4;
            ushort4 z; z.x = z.y = z.z = z.w = 0;
            if (g < NENT) {
                const float4* src = (const float4*)(emb_e + (long)g * 100);
#pragma unroll
                for (int jj = 0; jj < 7; jj++) {
                    int i = p + 4 * jj;
                    if (i < 25) {
                        float4 v = src[i];
                        ushort4 h;
                        h.x = f2bf(v.x); h.y = f2bf(v.y); h.z = f2bf(v.z); h.w = f2bf(v.w);
                        *(ushort4*)((char*)Es + ((rowb + 8u * i) ^ sw)) = h;
                    }
                }
            } else {
#pragma unroll
                for (int jj = 0; jj < 7; jj++) {
                    int i = p + 4 * jj;
                    if (i < 25) *(ushort4*)((char*)Es + ((rowb + 8u * i) ^ sw)) = z;
                }
            }
            // zero pad bytes 200..255 (cols 100..127)
            for (int z8 = p; z8 < 7; z8 += 4)
                *(ushort4*)((char*)Es + ((rowb + 200u + 8u * z8) ^ sw)) = z;
        }
    }
    __syncthreads();

    int w = tid >> 6, l = tid & 63;
    int l15 = l & 15, l4 = l >> 4;
    f32x4 acc[4][4];
#pragma unroll
    for (int i = 0; i < 4; i++)
#pragma unroll
        for (int j = 0; j < 4; j++) acc[i][j] = f32x4{0.f, 0.f, 0.f, 0.f};

#pragma unroll
    for (int ks = 0; ks < 4; ks++) {
        int kb = ks * 32 + l4 * 8;
        bf16x8 Af[4], Bf[4];
#pragma unroll
        for (int fm = 0; fm < 4; fm++) {
            int m = m0 + fm * 16 + l15;
            Af[fm] = *(const bf16x8*)(xhat + (long)m * 128 + kb);
        }
#pragma unroll
        for (int fn = 0; fn < 4; fn++) {
            int r = w * 64 + fn * 16 + l15;
            unsigned int byteoff = ((unsigned)(r * 256 + kb * 2)) ^ (((unsigned)r & 7u) << 4);
            Bf[fn] = *(const bf16x8*)((const char*)Es + byteoff);
        }
#pragma unroll
        for (int fm = 0; fm < 4; fm++)
#pragma unroll
            for (int fn = 0; fn < 4; fn++)
                acc[fm][fn] = __builtin_amdgcn_mfma_f32_16x16x32_bf16(Af[fm], Bf[fn], acc[fm][fn], 0, 0, 0);
    }

    // ---- epilogue: + bias, sigmoid, store ----
#pragma unroll
    for (int fn = 0; fn < 4; fn++) {
        int col = n0 + w * 64 + fn * 16 + l15;
        if (col < NENT) {
            float bv = bias[col];
#pragma unroll
            for (int fm = 0; fm < 4; fm++) {
                int rw = m0 + fm * 16 + l4 * 4;
#pragma unroll
                for (int r2 = 0; r2 < 4; r2++) {
                    float v = acc[fm][fn][r2] + bv;
                    float e = __expf(-v);
                    out[(long)(rw + r2) * NENT + col] = 1.0f / (1.0f + e);
                }
            }
        }
    }
}

extern "C" void kernel_launch(void* const* d_in, const int* in_sizes, int n_in,
                              void* d_out, int out_size, void* d_ws, size_t ws_size,
                              hipStream_t stream) {
    const int*   e1      = (const int*)d_in[0];
    const int*   rel     = (const int*)d_in[1];
    const float* emb_e   = (const float*)d_in[2];
    const float* emb_rel = (const float*)d_in[3];
    const float* fc_w    = (const float*)d_in[4];
    const float* fc_b    = (const float*)d_in[5];
    const float* bias    = (const float*)d_in[6];
    const float* g0      = (const float*)d_in[7];
    const float* b0      = (const float*)d_in[8];
    const float* g1      = (const float*)d_in[9];
    const float* b1      = (const float*)d_in[10];
    const float* grel    = (const float*)d_in[11];
    const float* brel    = (const float*)d_in[12];
    const float* g2      = (const float*)d_in[13];
    const float* b2      = (const float*)d_in[14];
    float* ws  = (float*)d_ws;
    float* out = (float*)d_out;

    hipLaunchKernelGGL(k_rel_stats, dim3(40), dim3(256), 0, stream, rel, emb_rel, grel, brel, ws);
    hipLaunchKernelGGL(k_e_stats, dim3(1), dim3(1024), 0, stream, e1, emb_e, g0, b0, ws);
    hipLaunchKernelGGL(k_conv, dim3(1024), dim3(256), 0, stream, e1, rel, emb_e, emb_rel, ws, ws + XBUF_OFF);
    hipLaunchKernelGGL(k_bn1_stats, dim3(100), dim3(256), 0, stream, ws + XBUF_OFF, g1, b1, ws);
    hipLaunchKernelGGL(k_fc, dim3(256, 4), dim3(256), 0, stream, ws + XBUF_OFF, fc_w, ws, ws + PART_OFF);
    hipLaunchKernelGGL(k_bn2, dim3(100), dim3(256), 0, stream, ws + PART_OFF, fc_b, g2, b2, ws + FCOUT_OFF, ws);
    hipLaunchKernelGGL(k_xhat, dim3(512), dim3(256), 0, stream, ws + FCOUT_OFF, ws, (unsigned short*)(ws + XHAT_OFF));
    hipLaunchKernelGGL(k_gemm, dim3(16, 391), dim3(256), 0, stream,
                       (const unsigned short*)(ws + XHAT_OFF), emb_e, bias, out);
}

// Round 2
// 356.966 us; speedup vs baseline: 1.3240x; 1.3240x over previous
//
#include <hip/hip_runtime.h>
#include <cstdint>

#define NENT 100000
#define EPS 1e-5f

// ---- ws layout (float offsets) ----
constexpr long REL_A    = 0;        // 2500
constexpr long REL_B    = 2500;     // 2500
constexpr long EPART    = 5000;     // 16 (8 blocks x {sum, sumsq})
constexpr long A1O      = 5056;     // 100
constexpr long C1O      = 5156;     // 100
constexpr long PART_OFF = 5504;     // 4*1024*100 = 409600
constexpr long XBUF_OFF = 415104;   // 1024*3600  = 3686400
constexpr long XHAT_OFF = 4101504;  // 1024*128 bf16 = 65536 floats (16B aligned)

typedef __attribute__((ext_vector_type(8))) __bf16 bf16x8;
typedef __attribute__((ext_vector_type(4))) float  f32x4;

__device__ __forceinline__ unsigned short f2bf(float f) {
    unsigned int u = __float_as_uint(f);
    unsigned int r = (u + 0x7FFFu + ((u >> 16) & 1u)) >> 16;
    return (unsigned short)r;
}

// K1: blocks 0..39 -> per-feature BN stats of gathered rel rows (scale/shift)
//     blocks 40..47 -> partial sums for scalar BN0 over gathered e rows
__global__ void k_stats(const int* __restrict__ rel, const float* __restrict__ emb_rel,
                        const float* __restrict__ grel, const float* __restrict__ brel,
                        const int* __restrict__ e1, const float* __restrict__ emb_e,
                        float* __restrict__ ws) {
    int tid = threadIdx.x;
    if (blockIdx.x < 40) {
        __shared__ int ridx[1024];
        __shared__ float psum[256], psq[256];
        for (int i = tid; i < 1024; i += 256) ridx[i] = rel[i];
        __syncthreads();
        int fl = tid & 63, bl = tid >> 6;
        int f = blockIdx.x * 64 + fl;
        float s = 0.f, q = 0.f;
        if (f < 2500) {
#pragma unroll 4
            for (int b = bl; b < 1024; b += 4) {
                float v = emb_rel[(long)ridx[b] * 2500 + f];
                s += v; q += v * v;
            }
        }
        psum[tid] = s; psq[tid] = q;
        __syncthreads();
        if (tid < 64 && f < 2500) {
            float ss = psum[tid] + psum[tid + 64] + psum[tid + 128] + psum[tid + 192];
            float qq = psq[tid]  + psq[tid + 64]  + psq[tid + 128]  + psq[tid + 192];
            float mean = ss * (1.f / 1024.f);
            float var  = qq * (1.f / 1024.f) - mean * mean;
            float a = grel[f] * rsqrtf(var + EPS);
            ws[REL_A + f] = a;
            ws[REL_B + f] = brel[f] - mean * a;
        }
    } else {
        __shared__ int eidx[128];
        __shared__ float ps[256], pq[256];
        int bi = blockIdx.x - 40;
        if (tid < 128) eidx[tid] = e1[bi * 128 + tid];
        __syncthreads();
        float s = 0.f, q = 0.f;
        for (int i = tid; i < 12800; i += 256) {
            int b = i / 100, d = i - b * 100;
            float v = emb_e[(long)eidx[b] * 100 + d];
            s += v; q += v * v;
        }
        ps[tid] = s; pq[tid] = q;
        __syncthreads();
        for (int off = 128; off > 0; off >>= 1) {
            if (tid < off) { ps[tid] += ps[tid + off]; pq[tid] += pq[tid + off]; }
            __syncthreads();
        }
        if (tid == 0) { ws[EPART + bi * 2] = ps[0]; ws[EPART + bi * 2 + 1] = pq[0]; }
    }
}

// K2: per-sample grouped conv 10x10 * (100 x 5x5) -> [B,100,6,6]
__global__ void k_conv(const int* __restrict__ e1, const int* __restrict__ rel,
                       const float* __restrict__ emb_e, const float* __restrict__ emb_rel,
                       const float* __restrict__ g0, const float* __restrict__ b0,
                       const float* __restrict__ ws, float* __restrict__ xout) {
    __shared__ float es[100];
    __shared__ float flt[2500];
    __shared__ float a0c0[2];
    int b = blockIdx.x, tid = threadIdx.x;
    if (tid == 0) {
        float s = 0.f, q = 0.f;
#pragma unroll
        for (int i = 0; i < 8; i++) { s += ws[EPART + 2 * i]; q += ws[EPART + 2 * i + 1]; }
        float mean = s * (1.f / 102400.f);
        float var  = q * (1.f / 102400.f) - mean * mean;
        float a = g0[0] * rsqrtf(var + EPS);
        a0c0[0] = a; a0c0[1] = b0[0] - mean * a;
    }
    __syncthreads();
    float a0 = a0c0[0], c0 = a0c0[1];
    long ebase = (long)e1[b] * 100;
    for (int i = tid; i < 100; i += 256) es[i] = a0 * emb_e[ebase + i] + c0;
    long rbase = (long)rel[b] * 2500;
    for (int i = tid; i < 2500; i += 256) flt[i] = ws[REL_A + i] * emb_rel[rbase + i] + ws[REL_B + i];
    __syncthreads();
    for (int u = tid; u < 600; u += 256) {
        int f = u / 6, oi = u - f * 6;
        float er[5][10];
#pragma unroll
        for (int p = 0; p < 5; p++)
#pragma unroll
            for (int c = 0; c < 10; c++) er[p][c] = es[(oi + p) * 10 + c];
        float fw[25];
#pragma unroll
        for (int k = 0; k < 25; k++) fw[k] = flt[f * 25 + k];
        float* dst = xout + (long)b * 3600 + f * 36 + oi * 6;
#pragma unroll
        for (int oj = 0; oj < 6; oj++) {
            float acc = 0.f;
#pragma unroll
            for (int p = 0; p < 5; p++)
#pragma unroll
                for (int q = 0; q < 5; q++) acc += er[p][oj + q] * fw[p * 5 + q];
            dst[oj] = acc;
        }
    }
}

// K3: per-channel BN1 stats over conv output
__global__ void k_bn1_stats(const float* __restrict__ xbuf, const float* __restrict__ g1,
                            const float* __restrict__ b1, float* __restrict__ ws) {
    __shared__ float ps[256], pq[256];
    int f = blockIdx.x, tid = threadIdx.x;
    float s = 0.f, q = 0.f;
    for (int i = tid; i < 1024 * 36; i += 256) {
        int b = i / 36, o = i - b * 36;
        float v = xbuf[(long)b * 3600 + f * 36 + o];
        s += v; q += v * v;
    }
    ps[tid] = s; pq[tid] = q;
    __syncthreads();
    for (int off = 128; off > 0; off >>= 1) {
        if (tid < off) { ps[tid] += ps[tid + off]; pq[tid] += pq[tid + off]; }
        __syncthreads();
    }
    if (tid == 0) {
        float mean = ps[0] * (1.f / 36864.f);
        float var  = pq[0] * (1.f / 36864.f) - mean * mean;
        float a = g1[f] * rsqrtf(var + EPS);
        ws[A1O + f] = a;
        ws[C1O + f] = b1[f] - mean * a;
    }
}

// K4: FC partials, K split in 4 chunks of 900.  block = (4 samples, 1 k-chunk)
__global__ void k_fc(const float* __restrict__ xbuf, const float* __restrict__ fc_w,
                     const float* __restrict__ ws, float* __restrict__ part) {
    __shared__ float a1s[100], c1s[100];
    __shared__ float xs[4][900];
    int tid = threadIdx.x;
    int sb = blockIdx.x, kc = blockIdx.y;
    if (tid < 100) { a1s[tid] = ws[A1O + tid]; c1s[tid] = ws[C1O + tid]; }
    __syncthreads();
    int b0 = sb * 4, k0 = kc * 900;
    for (int idx = tid; idx < 3600; idx += 256) {
        int s = idx / 900, k = idx - s * 900;
        int kg = k0 + k;
        int f = kg / 36;
        float v = xbuf[(long)(b0 + s) * 3600 + kg];
        v = a1s[f] * v + c1s[f];
        xs[s][k] = v > 0.f ? v : 0.f;
    }
    __syncthreads();
    if (tid < 200) {
        int j = tid % 100, sg = tid / 100;
        float acc0 = 0.f, acc1 = 0.f;
        const float4* wrow = (const float4*)(fc_w + (long)j * 3600 + k0);
        const float4* x0 = (const float4*)(&xs[sg][0]);
        const float4* x1 = (const float4*)(&xs[sg + 2][0]);
#pragma unroll 5
        for (int kk = 0; kk < 225; kk++) {
            float4 w4 = wrow[kk];
            float4 a4 = x0[kk], b4 = x1[kk];
            acc0 += w4.x * a4.x + w4.y * a4.y + w4.z * a4.z + w4.w * a4.w;
            acc1 += w4.x * b4.x + w4.y * b4.y + w4.z * b4.z + w4.w * b4.w;
        }
        part[((long)kc * 1024 + b0 + sg) * 100 + j]     = acc0;
        part[((long)kc * 1024 + b0 + sg + 2) * 100 + j] = acc1;
    }
}

// K5: combine FC partials + fc_b, per-feature BN2 stats, BN2-apply + ReLU -> xhat bf16 [1024][128]
__global__ void k_bn2x(const float* __restrict__ part, const float* __restrict__ fc_b,
                       const float* __restrict__ g2, const float* __restrict__ b2,
                       unsigned short* __restrict__ xhat) {
    int j = blockIdx.x, tid = threadIdx.x;
    if (j >= 100) {   // zero-pad columns 100..127
        for (int t = 0; t < 4; t++) xhat[(long)(tid + t * 256) * 128 + j] = 0;
        return;
    }
    __shared__ float ps[256], pq[256];
    __shared__ float ab[2];
    float v[4];
    float s = 0.f, q = 0.f;
#pragma unroll
    for (int t = 0; t < 4; t++) {
        int b = tid + t * 256;
        float x = part[(long)b * 100 + j] + part[(long)(1024 + b) * 100 + j]
                + part[(long)(2048 + b) * 100 + j] + part[(long)(3072 + b) * 100 + j]
                + fc_b[j];
        v[t] = x; s += x; q += x * x;
    }
    ps[tid] = s; pq[tid] = q;
    __syncthreads();
    for (int off = 128; off > 0; off >>= 1) {
        if (tid < off) { ps[tid] += ps[tid + off]; pq[tid] += pq[tid + off]; }
        __syncthreads();
    }
    if (tid == 0) {
        float mean = ps[0] * (1.f / 1024.f);
        float var  = pq[0] * (1.f / 1024.f) - mean * mean;
        float a = g2[j] * rsqrtf(var + EPS);
        ab[0] = a; ab[1] = b2[j] - mean * a;
    }
    __syncthreads();
    float a = ab[0], c = ab[1];
#pragma unroll
    for (int t = 0; t < 4; t++) {
        float x = a * v[t] + c;
        x = x > 0.f ? x : 0.f;
        xhat[(long)(tid + t * 256) * 128 + j] = f2bf(x);
    }
}

// K6: logits = Xhat @ emb_e^T + bias, sigmoid.  M=1024 N=100000 K=128(pad)
// One block per 128-ent N-tile; E staged ONCE in LDS (bf16, XOR-swizzled); M-loop inside.
// Operands swapped: mfma(E, X) -> acc reg-index runs along ent -> float4 stores.
__global__ void __launch_bounds__(256, 4)
k_gemm(const unsigned short* __restrict__ xhat, const float* __restrict__ emb_e,
       const float* __restrict__ bias, float* __restrict__ out) {
    __shared__ __align__(16) unsigned short Es[128 * 128];  // [row][col] bf16, byte ^= (row&7)<<4
    char* EsB = (char*)Es;
    int tid = threadIdx.x;
    int n0 = blockIdx.x * 128;

    // ---- stage E tile: 2 threads per row ----
    {
        int r = tid >> 1, p = tid & 1;
        int g = n0 + r;
        unsigned int rowb = (unsigned)r * 256u;
        unsigned int sw = ((unsigned)r & 7u) << 4;
        ushort4 z; z.x = z.y = z.z = z.w = 0;
        if (g < NENT) {
            const float4* src = (const float4*)(emb_e + (long)g * 100);
            for (int i = p; i < 25; i += 2) {
                float4 v = src[i];
                ushort4 h;
                h.x = f2bf(v.x); h.y = f2bf(v.y); h.z = f2bf(v.z); h.w = f2bf(v.w);
                *(ushort4*)(EsB + ((rowb + 8u * i) ^ sw)) = h;
            }
        } else {
            for (int i = p; i < 25; i += 2) *(ushort4*)(EsB + ((rowb + 8u * i) ^ sw)) = z;
        }
        for (int zz = p; zz < 7; zz += 2) *(ushort4*)(EsB + ((rowb + 200u + 8u * zz) ^ sw)) = z;
    }
    __syncthreads();

    int w = tid >> 6, l = tid & 63;
    int l15 = l & 15, l4 = l >> 4;

    // A (E) fragment addressing: row = w*32 + fe*16 + l15, byte col = ks*64 + l4*16
    unsigned int arow[2], asw[2];
#pragma unroll
    for (int fe = 0; fe < 2; fe++) {
        unsigned int r = (unsigned)(w * 32 + fe * 16 + l15);
        arow[fe] = r * 256u + (unsigned)(l4 * 16);
        asw[fe] = (r & 7u) << 4;
    }
    // bias + validity per fe (ent groups of 4)
    int gnb[2]; bool valid[2]; float4 bias4[2];
#pragma unroll
    for (int fe = 0; fe < 2; fe++) {
        gnb[fe] = n0 + w * 32 + fe * 16 + l4 * 4;
        valid[fe] = gnb[fe] < NENT;
        bias4[fe] = valid[fe] ? *(const float4*)(bias + gnb[fe]) : float4{0.f, 0.f, 0.f, 0.f};
    }
    int xrow = l15 * 128 + l4 * 8;   // element offset into xhat

    for (int chunk = 0; chunk < 16; ++chunk) {
        int m0 = chunk * 64;
        f32x4 acc[2][4];
#pragma unroll
        for (int fe = 0; fe < 2; fe++)
#pragma unroll
            for (int fx = 0; fx < 4; fx++) acc[fe][fx] = f32x4{0.f, 0.f, 0.f, 0.f};

#pragma unroll
        for (int ks = 0; ks < 4; ++ks) {
            bf16x8 Af[2], Bf[4];
#pragma unroll
            for (int fe = 0; fe < 2; fe++)
                Af[fe] = *(const bf16x8*)(EsB + ((arow[fe] + (unsigned)(ks * 64)) ^ asw[fe]));
#pragma unroll
            for (int fx = 0; fx < 4; fx++)
                Bf[fx] = *(const bf16x8*)(xhat + (long)(m0 * 128 + fx * 2048 + ks * 32 + xrow));
#pragma unroll
            for (int fe = 0; fe < 2; fe++)
#pragma unroll
                for (int fx = 0; fx < 4; fx++)
                    acc[fe][fx] = __builtin_amdgcn_mfma_f32_16x16x32_bf16(Af[fe], Bf[fx], acc[fe][fx], 0, 0, 0);
        }

        // epilogue: + bias, sigmoid, float4 stores
#pragma unroll
        for (int fe = 0; fe < 2; fe++) {
            if (!valid[fe]) continue;
#pragma unroll
            for (int fx = 0; fx < 4; fx++) {
                int m = m0 + fx * 16 + l15;
                float4 o;
#pragma unroll
                for (int r2 = 0; r2 < 4; r2++) {
                    float x = acc[fe][fx][r2] + ((const float*)&bias4[fe])[r2];
                    float e = __builtin_amdgcn_exp2f(x * -1.44269504f);
                    o.x = o.x;  // no-op to keep struct init simple
                    ((float*)&o)[r2] = __builtin_amdgcn_rcpf(1.0f + e);
                }
                *(float4*)(out + (long)m * NENT + gnb[fe]) = o;
            }
        }
    }
}

extern "C" void kernel_launch(void* const* d_in, const int* in_sizes, int n_in,
                              void* d_out, int out_size, void* d_ws, size_t ws_size,
                              hipStream_t stream) {
    const int*   e1      = (const int*)d_in[0];
    const int*   rel     = (const int*)d_in[1];
    const float* emb_e   = (const float*)d_in[2];
    const float* emb_rel = (const float*)d_in[3];
    const float* fc_w    = (const float*)d_in[4];
    const float* fc_b    = (const float*)d_in[5];
    const float* bias    = (const float*)d_in[6];
    const float* g0      = (const float*)d_in[7];
    const float* b0      = (const float*)d_in[8];
    const float* g1      = (const float*)d_in[9];
    const float* b1      = (const float*)d_in[10];
    const float* grel    = (const float*)d_in[11];
    const float* brel    = (const float*)d_in[12];
    const float* g2      = (const float*)d_in[13];
    const float* b2      = (const float*)d_in[14];
    float* ws  = (float*)d_ws;
    float* out = (float*)d_out;

    hipLaunchKernelGGL(k_stats, dim3(48), dim3(256), 0, stream, rel, emb_rel, grel, brel, e1, emb_e, ws);
    hipLaunchKernelGGL(k_conv, dim3(1024), dim3(256), 0, stream, e1, rel, emb_e, emb_rel, g0, b0, ws, ws + XBUF_OFF);
    hipLaunchKernelGGL(k_bn1_stats, dim3(100), dim3(256), 0, stream, ws + XBUF_OFF, g1, b1, ws);
    hipLaunchKernelGGL(k_fc, dim3(256, 4), dim3(256), 0, stream, ws + XBUF_OFF, fc_w, ws, ws + PART_OFF);
    hipLaunchKernelGGL(k_bn2x, dim3(128), dim3(256), 0, stream, ws + PART_OFF, fc_b, g2, b2,
                       (unsigned short*)(ws + XHAT_OFF));
    hipLaunchKernelGGL(k_gemm, dim3(782), dim3(256), 0, stream,
                       (const unsigned short*)(ws + XHAT_OFF), emb_e, bias, out);
}